// Round 5
// baseline (186.568 us; speedup 1.0000x reference)
//
#include <hip/hip_runtime.h>

// ALSTM: adaptive-computation-time LSTM.
//  - sum(w)==1  =>  output = (w@H)@W_out^T + b_out ; only hbar/cbar needed.
//  - steps after halting have w==0 and cannot affect n => early exit exact
//    (b_halt=1 => p0~0.73, halts at t=1: only 2 of 101 steps run).
// R4 post-mortem: compiler SANK the W_hh "register prefetch" back into the
// loop (VGPR_Count stayed 60) -- legal for const loads. R5: empty
// asm volatile "+v" ties after the load burst make the values opaque
// register defs the compiler cannot rematerialize from memory.

#define HID    2048
#define INS    1024
#define OUTS   1024
#define MSTEPS 100
#define NBLK   256
#define NTHR   1024
#define NWAVE  16
#define JPB    8      // hidden units owned per block (256*8 = 2048)
#define RPB    32     // gate rows per block (4 gates * JPB)

#define KEEP4(v) asm volatile("" : "+v"((v).x), "+v"((v).y), "+v"((v).z), "+v"((v).w))

__device__ __forceinline__ float wave_reduce(float v) {
    #pragma unroll
    for (int off = 32; off > 0; off >>= 1)
        v += __shfl_down(v, off, 64);
    return v;  // lane 0 holds the sum
}

// ws layout (floats): [0..128) halt-dot slots | [128] barrier counter |
// [256..2304) h buf0 | [2304..4352) h buf1 | [4352..6400) hbar_g.
// kernel_launch zeroes the first 1024 bytes each call.

__global__ __launch_bounds__(NTHR) void alstm_kernel(
    const float* __restrict__ x,      const float* __restrict__ h0,
    const float* __restrict__ c0,     const float* __restrict__ W_ih,
    const float* __restrict__ b_ih,   const float* __restrict__ W_hh,
    const float* __restrict__ b_hh,   const float* __restrict__ w_halt,
    const float* __restrict__ b_halt, const float* __restrict__ W_out,
    const float* __restrict__ b_out,  float* __restrict__ out,
    float* __restrict__ ws)
{
    const int b    = blockIdx.x;
    const int tid  = threadIdx.x;
    const int wave = tid >> 6;
    const int lane = tid & 63;

    float*    slots  = ws;                  // [128] halt-dot accumulators
    unsigned* bar    = (unsigned*)(ws + 128);
    float*    hbuf0  = ws + 256;            // [2048]
    float*    hbuf1  = ws + 256 + HID;      // [2048]
    float*    hbar_g = ws + 256 + 2 * HID;  // [2048] pooled h

    unsigned bar_target = 0;
    #define GBAR() do {                                                        \
        __syncthreads();                                                       \
        if (tid == 0) {                                                        \
            bar_target += NBLK;                                                \
            __hip_atomic_fetch_add(bar, 1u, __ATOMIC_ACQ_REL,                  \
                                   __HIP_MEMORY_SCOPE_AGENT);                  \
            while (__hip_atomic_load(bar, __ATOMIC_ACQUIRE,                    \
                                     __HIP_MEMORY_SCOPE_AGENT) < bar_target)   \
                __builtin_amdgcn_s_sleep(1);                                   \
        }                                                                      \
        __syncthreads();                                                       \
    } while (0)

    __shared__ float h_lds[HID];
    __shared__ float gate_lds[RPB];
    __shared__ float ihx_lds[RPB];
    __shared__ float wflag_lds[RPB];
    __shared__ float psum[NWAVE];

    const float bh = b_halt[0];
    const int j_own = b * JPB + tid;        // valid when tid < JPB

    // Local rows for this wave: lr0, lr0+1
    const int lr0 = 2 * wave;
    const int g   = lr0 >> 3;               // gate 0..3
    const int jj0 = lr0 & 7;                // unit offset
    const int r0  = g * HID + b * JPB + jj0;

    // ---- register prefetch burst: W_hh (2 rows/wave) + W_out slice ----
    float4 w0r[8], w1r[8];
    {
        const float4* wrow0 = (const float4*)(W_hh + (size_t)r0 * HID);
        const float4* wrow1 = (const float4*)(W_hh + (size_t)(r0 + 1) * HID);
        #pragma unroll
        for (int m = 0; m < 8; ++m) {
            w0r[m] = wrow0[lane + 64 * m];
            w1r[m] = wrow1[lane + 64 * m];
        }
    }
    const int orow = b * 4 + (wave & 3);    // W_out row for epilogue
    const int oq   = wave >> 2;             // quarter of the dot
    float4 wo0, wo1;
    {
        const float4* wor = (const float4*)(W_out + (size_t)orow * HID) + oq * 128;
        wo0 = wor[lane];
        wo1 = wor[lane + 64];
    }

    // ------------- prologue: ih_x (W_ih[:,1:]@x + b_ih + b_hh) -------------
    // (overlaps the prefetch burst's latency)
    for (int k = tid; k < INS; k += NTHR) h_lds[k] = x[k];
    __syncthreads();

    #pragma unroll
    for (int rr = 0; rr < 2; ++rr) {
        const int r = r0 + rr;
        const float* wrow = W_ih + (size_t)r * (INS + 1) + 1;  // payload, 1024
        const int mis = (r + 1) & 3;
        const int p0  = (4 - mis) & 3;
        const int nv  = (INS - p0) >> 2;
        const float4* wv = (const float4*)(wrow + p0);
        float acc = 0.f;
        for (int i = lane; i < nv; i += 64) {
            float4 w4 = wv[i];
            int k = p0 + 4 * i;
            acc += w4.x * h_lds[k] + w4.y * h_lds[k + 1]
                 + w4.z * h_lds[k + 2] + w4.w * h_lds[k + 3];
        }
        if (lane == 0) {
            for (int k = 0; k < p0; ++k)            acc += wrow[k] * h_lds[k];
            for (int k = p0 + 4 * nv; k < INS; ++k) acc += wrow[k] * h_lds[k];
        }
        acc = wave_reduce(acc);
        if (lane == 0) {
            ihx_lds[lr0 + rr]   = acc + b_ih[r] + b_hh[r];
            wflag_lds[lr0 + rr] = W_ih[(size_t)r * (INS + 1)];
        }
    }

    // Tie prefetched weights to registers: opaque redefinition -- the
    // compiler can no longer rematerialize these loads inside the loop.
    #pragma unroll
    for (int m = 0; m < 8; ++m) { KEEP4(w0r[m]); KEEP4(w1r[m]); }
    KEEP4(wo0); KEEP4(wo1);

    float c_reg = 0.f, h_reg = 0.f, hbar = 0.f, cbar = 0.f;
    if (tid < JPB) c_reg = c0[j_own];
    __syncthreads();   // h_lds (x) reads done before step-0 staging

    // ------------- recurrence with online halting -------------
    float csum = 0.f, r_halt = 0.f;
    int   n_halt = 0;
    for (int t = 0; t <= MSTEPS; ++t) {
        const float* hsrc = (t == 0) ? h0 : ((t & 1) ? hbuf1 : hbuf0);
        float* hdst = ((t & 1) ? hbuf0 : hbuf1);   // buffer for h_{t+1}
        ((float2*)h_lds)[tid] = ((const float2*)hsrc)[tid];
        __syncthreads();

        // 2 gate-rows per wave, weights in registers, h from LDS
        {
            const float4* hv = (const float4*)h_lds;
            float acc0 = 0.f, acc1 = 0.f;
            #pragma unroll
            for (int m = 0; m < 8; ++m) {
                float4 hh = hv[lane + 64 * m];
                acc0 += w0r[m].x * hh.x + w0r[m].y * hh.y
                      + w0r[m].z * hh.z + w0r[m].w * hh.w;
                acc1 += w1r[m].x * hh.x + w1r[m].y * hh.y
                      + w1r[m].z * hh.z + w1r[m].w * hh.w;
            }
            acc0 = wave_reduce(acc0);
            acc1 = wave_reduce(acc1);
            if (lane == 0) {
                float b0 = ihx_lds[lr0], b1 = ihx_lds[lr0 + 1];
                if (t == 0) { b0 += wflag_lds[lr0]; b1 += wflag_lds[lr0 + 1]; }
                gate_lds[lr0]     = b0 + acc0;
                gate_lds[lr0 + 1] = b1 + acc1;
            }
        }
        __syncthreads();

        float part = 0.f;
        if (tid < JPB) {
            float iv = gate_lds[0 * JPB + tid];
            float fv = gate_lds[1 * JPB + tid];
            float gv = gate_lds[2 * JPB + tid];
            float ov = gate_lds[3 * JPB + tid];
            iv = 1.f / (1.f + expf(-iv));
            fv = 1.f / (1.f + expf(-fv));
            gv = tanhf(gv);
            ov = 1.f / (1.f + expf(-ov));
            c_reg = fv * c_reg + iv * gv;
            h_reg = ov * tanhf(c_reg);
            hdst[j_own] = h_reg;
            part = h_reg * w_halt[j_own];
        }
        part += __shfl_down(part, 4, 64);
        part += __shfl_down(part, 2, 64);
        part += __shfl_down(part, 1, 64);
        if (tid == 0) atomicAdd(&slots[t], part);   // device-scope

        GBAR();   // hdst + slots[t] globally visible; h_lds reads done

        float dotv = __hip_atomic_load(&slots[t], __ATOMIC_RELAXED,
                                       __HIP_MEMORY_SCOPE_AGENT);
        float p = 1.f / (1.f + expf(-(dotv + bh)));
        float prev = csum;
        csum += p;
        bool halt_now = (csum >= 1.f - 0.01f) || (t == MSTEPS);
        float wt = halt_now ? (1.f - prev) : p;
        if (tid < JPB) { hbar += wt * h_reg; cbar += wt * c_reg; }
        if (halt_now) { n_halt = t; r_halt = 1.f - prev; break; }  // uniform
    }

    // ------------- epilogue -------------
    if (tid < JPB) {
        out[OUTS + j_own]       = hbar;   // h_out
        out[OUTS + HID + j_own] = cbar;   // c_out
        hbar_g[j_own] = hbar;
    }
    if (b == 0 && tid == 0) out[OUTS + 2 * HID] = (float)(n_halt + 1) + r_halt;

    GBAR();   // hbar_g visible

    ((float2*)h_lds)[tid] = ((const float2*)hbar_g)[tid];
    __syncthreads();

    // output = W_out @ hbar + b_out : quarter-row per wave, weights in regs
    {
        const float4* hv = (const float4*)h_lds + oq * 128;
        float4 h0v = hv[lane], h1v = hv[lane + 64];
        float acc = wo0.x * h0v.x + wo0.y * h0v.y + wo0.z * h0v.z + wo0.w * h0v.w
                  + wo1.x * h1v.x + wo1.y * h1v.y + wo1.z * h1v.z + wo1.w * h1v.w;
        acc = wave_reduce(acc);
        if (lane == 0) psum[wave] = acc;
    }
    __syncthreads();
    if (tid < 4) {
        int row = b * 4 + tid;
        float s = psum[tid] + psum[tid + 4] + psum[tid + 8] + psum[tid + 12];
        out[row] = s + b_out[row];
    }
    #undef GBAR
}

extern "C" void kernel_launch(void* const* d_in, const int* in_sizes, int n_in,
                              void* d_out, int out_size, void* d_ws, size_t ws_size,
                              hipStream_t stream) {
    const float* x      = (const float*)d_in[0];
    const float* h0     = (const float*)d_in[1];
    const float* c0     = (const float*)d_in[2];
    const float* W_ih   = (const float*)d_in[3];
    const float* b_ih   = (const float*)d_in[4];
    const float* W_hh   = (const float*)d_in[5];
    const float* b_hh   = (const float*)d_in[6];
    const float* w_halt = (const float*)d_in[7];
    const float* b_halt = (const float*)d_in[8];
    const float* W_out  = (const float*)d_in[9];
    const float* b_out  = (const float*)d_in[10];
    float* out = (float*)d_out;
    float* ws  = (float*)d_ws;

    // Zero halt slots + barrier counter (ws is poisoned 0xAA by the harness).
    hipMemsetAsync(d_ws, 0, 1024, stream);

    alstm_kernel<<<dim3(NBLK), dim3(NTHR), 0, stream>>>(
        x, h0, c0, W_ih, b_ih, W_hh, b_hh, w_halt, b_halt, W_out, b_out,
        out, ws);
}

// Round 6
// 178.497 us; speedup vs baseline: 1.0452x; 1.0452x over previous
//
#include <hip/hip_runtime.h>

// ALSTM: adaptive-computation-time LSTM.
//  - sum(w)==1  =>  output = (w@H)@W_out^T + b_out ; only hbar/cbar needed.
//  - steps after halting have w==0 and cannot affect n => early exit exact
//    (b_halt=1 => p0~0.73, halts at t=1: only 2 of 101 steps run).
// R5 post-mortem: ~60 of 71 us was coherence-point serialization (256
// same-address atomicAdds/step + counter-barrier RMW storm). R6: mailbox
// barrier fused with the halt-dot reduction -- per-block arrive slots,
// block 0 gathers+reduces+broadcasts to per-block mailboxes. No shared-line
// RMWs anywhere. Register prefetch dropped (defeated twice; streaming is
// only ~6 us of the budget).

#define HID    2048
#define INS    1024
#define OUTS   1024
#define MSTEPS 100
#define NBLK   256
#define NTHR   1024
#define NWAVE  16
#define JPB    8      // hidden units owned per block (256*8 = 2048)
#define RPB    32     // gate rows per block (4 gates * JPB)

typedef unsigned long long u64;

__device__ __forceinline__ float wave_reduce(float v) {
    #pragma unroll
    for (int off = 32; off > 0; off >>= 1)
        v += __shfl_down(v, off, 64);
    return v;  // lane 0 holds the sum
}

__device__ __forceinline__ u64 pack_tag(unsigned tag, float v) {
    return ((u64)tag << 32) | (u64)__float_as_uint(v);
}
__device__ __forceinline__ u64 aload(const u64* p) {
    return __hip_atomic_load(p, __ATOMIC_RELAXED, __HIP_MEMORY_SCOPE_AGENT);
}
__device__ __forceinline__ void astore(u64* p, u64 v) {
    __hip_atomic_store(p, v, __ATOMIC_RELAXED, __HIP_MEMORY_SCOPE_AGENT);
}

// ws layout (floats):
//   [0..1024)    arrive slots: 256 x 16B (u64-tagged {tag, partial})
//   [1024..2048) mailboxes:    256 x 16B (u64-tagged {tag, dot})
//   [2048..4096) hbuf0 | [4096..6144) hbuf1 | [6144..8192) hbar_g
// kernel_launch zeroes the first 8192 bytes (arrive+mailbox) each call.

__global__ __launch_bounds__(NTHR) void alstm_kernel(
    const float* __restrict__ x,      const float* __restrict__ h0,
    const float* __restrict__ c0,     const float* __restrict__ W_ih,
    const float* __restrict__ b_ih,   const float* __restrict__ W_hh,
    const float* __restrict__ b_hh,   const float* __restrict__ w_halt,
    const float* __restrict__ b_halt, const float* __restrict__ W_out,
    const float* __restrict__ b_out,  float* __restrict__ out,
    float* __restrict__ ws)
{
    const int b    = blockIdx.x;
    const int tid  = threadIdx.x;
    const int wave = tid >> 6;
    const int lane = tid & 63;

    float* arrive = ws;                 // 256 x 4 floats (u64 in [0:2))
    float* mail   = ws + 1024;          // 256 x 4 floats
    float* hbuf0  = ws + 2048;
    float* hbuf1  = ws + 2048 + HID;
    float* hbar_g = ws + 2048 + 2 * HID;

    __shared__ float h_lds[HID];
    __shared__ float x_lds[INS];
    __shared__ float gate_lds[RPB];
    __shared__ float ihx_lds[RPB];
    __shared__ float wflag_lds[RPB];
    __shared__ float red_lds[4];
    __shared__ float bcast_lds;
    __shared__ float psum[NWAVE];

    const float bh = b_halt[0];
    const int j_own = b * JPB + tid;    // valid when tid < JPB

    // Rows for this wave: lr0, lr0+1
    const int lr0 = 2 * wave;
    const int g   = lr0 >> 3;
    const int jj0 = lr0 & 7;
    const int r0  = g * HID + b * JPB + jj0;

    // ---- Fused sync + halt-dot round: producer side + block-0 gather ----
    // Producer: write own arrive slot {tag, part}. Gatherer (block 0):
    // poll all 256, reduce, broadcast {tag, dot} to per-block mailboxes.
    // Consumer: poll own mailbox. No shared-line RMWs.
    #define SYNC_ROUND(tag_, part_, dot_) do {                                 \
        if (tid == 0) {                                                        \
            __threadfence();   /* wb: h/other stores reach coherence pt */     \
            astore((u64*)(arrive + 4 * b), pack_tag((tag_), (part_)));         \
        }                                                                      \
        if (b == 0) {                                                          \
            float pf = 0.f;                                                    \
            if (tid < NBLK) {                                                  \
                u64 v;                                                         \
                do { v = aload((u64*)(arrive + 4 * tid)); }                    \
                while ((unsigned)(v >> 32) != (tag_));                         \
                pf = __uint_as_float((unsigned)v);                             \
            }                                                                  \
            float s = wave_reduce(pf);                                         \
            if (lane == 0 && wave < 4) red_lds[wave] = s;                      \
            __syncthreads();                                                   \
            if (tid == 0)                                                      \
                bcast_lds = red_lds[0] + red_lds[1] + red_lds[2] + red_lds[3]; \
            __syncthreads();                                                   \
            if (tid < NBLK)                                                    \
                astore((u64*)(mail + 4 * tid), pack_tag((tag_), bcast_lds));   \
        }                                                                      \
        if (tid == 0) {                                                        \
            u64 v;                                                             \
            do { v = aload((u64*)(mail + 4 * b)); }                            \
            while ((unsigned)(v >> 32) != (tag_));                             \
            bcast_lds = __uint_as_float((unsigned)v);                          \
            __threadfence();   /* inv: later plain reads see fresh data */     \
        }                                                                      \
        __syncthreads();                                                       \
        (dot_) = bcast_lds;                                                    \
    } while (0)

    // ------------- stage x and h0; one overlapped burst -------------
    if (tid < INS / 2) ((float2*)x_lds)[tid] = ((const float2*)x)[tid];
    ((float2*)h_lds)[tid] = ((const float2*)h0)[tid];
    __syncthreads();

    // ih_x = W_ih[:,1:]@x + b_ih + b_hh  (2 rows/wave, from x_lds)
    #pragma unroll
    for (int rr = 0; rr < 2; ++rr) {
        const int r = r0 + rr;
        const float* wrow = W_ih + (size_t)r * (INS + 1) + 1;  // 1024 payload
        const int mis = (r + 1) & 3;
        const int p0  = (4 - mis) & 3;
        const int nv  = (INS - p0) >> 2;
        const float4* wv = (const float4*)(wrow + p0);
        float acc = 0.f;
        for (int i = lane; i < nv; i += 64) {
            float4 w4 = wv[i];
            int k = p0 + 4 * i;
            acc += w4.x * x_lds[k] + w4.y * x_lds[k + 1]
                 + w4.z * x_lds[k + 2] + w4.w * x_lds[k + 3];
        }
        if (lane == 0) {
            for (int k = 0; k < p0; ++k)            acc += wrow[k] * x_lds[k];
            for (int k = p0 + 4 * nv; k < INS; ++k) acc += wrow[k] * x_lds[k];
        }
        acc = wave_reduce(acc);
        if (lane == 0) {
            ihx_lds[lr0 + rr]   = acc + b_ih[r] + b_hh[r];
            wflag_lds[lr0 + rr] = W_ih[(size_t)r * (INS + 1)];
        }
    }

    float c_reg = 0.f, h_reg = 0.f, hbar = 0.f, cbar = 0.f;
    if (tid < JPB) c_reg = c0[j_own];

    const float4* wrow0 = (const float4*)(W_hh + (size_t)r0 * HID);
    const float4* wrow1 = (const float4*)(W_hh + (size_t)(r0 + 1) * HID);

    // ------------- recurrence with online halting -------------
    float csum = 0.f, r_halt = 0.f;
    int   n_halt = 0;
    for (int t = 0; t <= MSTEPS; ++t) {
        // h for this step already in h_lds (h0 at t=0; staged at loop end)
        {
            const float4* hv = (const float4*)h_lds;
            float acc0 = 0.f, acc1 = 0.f;
            #pragma unroll
            for (int m = 0; m < 8; ++m) {
                float4 hh = hv[lane + 64 * m];
                float4 w0 = wrow0[lane + 64 * m];
                float4 w1 = wrow1[lane + 64 * m];
                acc0 += w0.x * hh.x + w0.y * hh.y + w0.z * hh.z + w0.w * hh.w;
                acc1 += w1.x * hh.x + w1.y * hh.y + w1.z * hh.z + w1.w * hh.w;
            }
            acc0 = wave_reduce(acc0);
            acc1 = wave_reduce(acc1);
            if (lane == 0) {
                float b0 = ihx_lds[lr0], b1 = ihx_lds[lr0 + 1];
                if (t == 0) { b0 += wflag_lds[lr0]; b1 += wflag_lds[lr0 + 1]; }
                gate_lds[lr0]     = b0 + acc0;
                gate_lds[lr0 + 1] = b1 + acc1;
            }
        }
        __syncthreads();

        float part = 0.f;
        float* hdst = (t & 1) ? hbuf1 : hbuf0;
        if (tid < JPB) {
            float iv = gate_lds[0 * JPB + tid];
            float fv = gate_lds[1 * JPB + tid];
            float gv = gate_lds[2 * JPB + tid];
            float ov = gate_lds[3 * JPB + tid];
            iv = 1.f / (1.f + expf(-iv));
            fv = 1.f / (1.f + expf(-fv));
            gv = tanhf(gv);
            ov = 1.f / (1.f + expf(-ov));
            c_reg = fv * c_reg + iv * gv;
            h_reg = ov * tanhf(c_reg);
            hdst[j_own] = h_reg;
            part = h_reg * w_halt[j_own];
        }
        part += __shfl_down(part, 4, 64);
        part += __shfl_down(part, 2, 64);
        part += __shfl_down(part, 1, 64);

        float dotv;
        SYNC_ROUND(t + 1, part, dotv);

        float p = 1.f / (1.f + expf(-(dotv + bh)));
        float prev = csum;
        csum += p;
        bool halt_now = (csum >= 1.f - 0.01f) || (t == MSTEPS);
        float wt = halt_now ? (1.f - prev) : p;
        if (tid < JPB) { hbar += wt * h_reg; cbar += wt * c_reg; }
        if (halt_now) { n_halt = t; r_halt = 1.f - prev; break; }  // uniform

        // stage h_{t+1} for next iteration
        __syncthreads();   // gate_lds/h_lds reads done
        ((float2*)h_lds)[tid] = ((const float2*)hdst)[tid];
        __syncthreads();
    }

    // ------------- epilogue -------------
    if (tid < JPB) {
        out[OUTS + j_own]       = hbar;   // h_out
        out[OUTS + HID + j_own] = cbar;   // c_out
        hbar_g[j_own] = hbar;
    }
    if (b == 0 && tid == 0) out[OUTS + 2 * HID] = (float)(n_halt + 1) + r_halt;

    float dummy;
    SYNC_ROUND(n_halt + 2, 0.f, dummy);
    (void)dummy;

    __syncthreads();
    ((float2*)h_lds)[tid] = ((const float2*)hbar_g)[tid];
    __syncthreads();

    // output = W_out @ hbar + b_out : quarter-row per wave
    {
        const int row = b * 4 + (wave & 3);
        const int q   = wave >> 2;
        const float4* wrow = (const float4*)(W_out + (size_t)row * HID) + q * 128;
        const float4* hv   = (const float4*)h_lds + q * 128;
        float4 w0 = wrow[lane],      h0v = hv[lane];
        float4 w1 = wrow[lane + 64], h1v = hv[lane + 64];
        float acc = w0.x * h0v.x + w0.y * h0v.y + w0.z * h0v.z + w0.w * h0v.w
                  + w1.x * h1v.x + w1.y * h1v.y + w1.z * h1v.z + w1.w * h1v.w;
        acc = wave_reduce(acc);
        if (lane == 0) psum[wave] = acc;
    }
    __syncthreads();
    if (tid < 4) {
        int row = b * 4 + tid;
        float s = psum[tid] + psum[tid + 4] + psum[tid + 8] + psum[tid + 12];
        out[row] = s + b_out[row];
    }
    #undef SYNC_ROUND
}

extern "C" void kernel_launch(void* const* d_in, const int* in_sizes, int n_in,
                              void* d_out, int out_size, void* d_ws, size_t ws_size,
                              hipStream_t stream) {
    const float* x      = (const float*)d_in[0];
    const float* h0     = (const float*)d_in[1];
    const float* c0     = (const float*)d_in[2];
    const float* W_ih   = (const float*)d_in[3];
    const float* b_ih   = (const float*)d_in[4];
    const float* W_hh   = (const float*)d_in[5];
    const float* b_hh   = (const float*)d_in[6];
    const float* w_halt = (const float*)d_in[7];
    const float* b_halt = (const float*)d_in[8];
    const float* W_out  = (const float*)d_in[9];
    const float* b_out  = (const float*)d_in[10];
    float* out = (float*)d_out;
    float* ws  = (float*)d_ws;

    // Zero arrive slots + mailboxes (ws is poisoned 0xAA by the harness).
    hipMemsetAsync(d_ws, 0, 8192, stream);

    alstm_kernel<<<dim3(NBLK), dim3(NTHR), 0, stream>>>(
        x, h0, c0, W_ih, b_ih, W_hh, b_hh, w_halt, b_halt, W_out, b_out,
        out, ws);
}